// Round 1
// baseline (375.627 us; speedup 1.0000x reference)
//
#include <hip/hip_runtime.h>
#include <hip/hip_bf16.h>

#define DEG 7
#define D1 8
#define RANK 8

__global__ __launch_bounds__(256) void tt_poly_kernel(
    const float* __restrict__ X,
    const float* __restrict__ G0,   // [d1, r]
    const float* __restrict__ G1,   // [r, d1, r]
    const float* __restrict__ G2,   // [r, d1, r]
    const float* __restrict__ G3,   // [r, d1]
    float* __restrict__ out,
    int B)
{
    int b = blockIdx.x * blockDim.x + threadIdx.x;
    if (b >= B) return;

    float4 x = reinterpret_cast<const float4*>(X)[b];

    // ---- stage 1: t0[r] = sum_d x0^d * G0[d][r], Horner over d ----
    float t0[RANK];
    #pragma unroll
    for (int r = 0; r < RANK; ++r) t0[r] = G0[(D1 - 1) * RANK + r];
    #pragma unroll
    for (int d = D1 - 2; d >= 0; --d) {
        #pragma unroll
        for (int r = 0; r < RANK; ++r)
            t0[r] = t0[r] * x.x + G0[d * RANK + r];
    }

    // ---- stage 2: t1[s] = sum_{r,d} t0[r] * G1[r][d][s] * x1^d ----
    // Horner over d with vector coefficients c_d[s] = sum_r t0[r]*G1[r][d][s]
    float t1[RANK];
    {
        #pragma unroll
        for (int s = 0; s < RANK; ++s) {
            float c = 0.f;
            #pragma unroll
            for (int r = 0; r < RANK; ++r)
                c += t0[r] * G1[(r * D1 + (D1 - 1)) * RANK + s];
            t1[s] = c;
        }
        #pragma unroll
        for (int d = D1 - 2; d >= 0; --d) {
            #pragma unroll
            for (int s = 0; s < RANK; ++s) {
                float c = 0.f;
                #pragma unroll
                for (int r = 0; r < RANK; ++r)
                    c += t0[r] * G1[(r * D1 + d) * RANK + s];
                t1[s] = t1[s] * x.y + c;
            }
        }
    }

    // ---- stage 3: t2[t] = sum_{s,d} t1[s] * G2[s][d][t] * x2^d ----
    float t2[RANK];
    {
        #pragma unroll
        for (int s = 0; s < RANK; ++s) {
            float c = 0.f;
            #pragma unroll
            for (int r = 0; r < RANK; ++r)
                c += t1[r] * G2[(r * D1 + (D1 - 1)) * RANK + s];
            t2[s] = c;
        }
        #pragma unroll
        for (int d = D1 - 2; d >= 0; --d) {
            #pragma unroll
            for (int s = 0; s < RANK; ++s) {
                float c = 0.f;
                #pragma unroll
                for (int r = 0; r < RANK; ++r)
                    c += t1[r] * G2[(r * D1 + d) * RANK + s];
                t2[s] = t2[s] * x.z + c;
            }
        }
    }

    // ---- stage 4: res = sum_{t,d} t2[t] * G3[t][d] * x3^d, Horner over d ----
    float res = 0.f;
    #pragma unroll
    for (int d = D1 - 1; d >= 0; --d) {
        float e = 0.f;
        #pragma unroll
        for (int t = 0; t < RANK; ++t)
            e += t2[t] * G3[t * D1 + d];
        res = res * x.w + e;
    }

    out[b] = res;
}

extern "C" void kernel_launch(void* const* d_in, const int* in_sizes, int n_in,
                              void* d_out, int out_size, void* d_ws, size_t ws_size,
                              hipStream_t stream) {
    const float* X  = (const float*)d_in[0];
    const float* G0 = (const float*)d_in[1];
    const float* G1 = (const float*)d_in[2];
    const float* G2 = (const float*)d_in[3];
    const float* G3 = (const float*)d_in[4];
    float* out = (float*)d_out;

    int B = in_sizes[0] / 4;   // X is [B,4]
    int block = 256;
    int grid = (B + block - 1) / block;
    tt_poly_kernel<<<grid, block, 0, stream>>>(X, G0, G1, G2, G3, out, B);
}